// Round 6
// baseline (136.786 us; speedup 1.0000x reference)
//
#include <hip/hip_runtime.h>

#define NBINS 15

typedef float f32x4 __attribute__((ext_vector_type(4)));
typedef int   i32x4 __attribute__((ext_vector_type(4)));

// Workspace layout (u64 each): [0..14] per-bin signed sum of wv*(c-corr) in
// 2^-16 fixed point (two's-complement wrapped), [15] total mask sum.
// ECE = sum_b |S_b| / 2^16 / total.  (counts/safe are provably redundant:
// empty bins contribute 0 in both formulations.)

__global__ __launch_bounds__(256, 8) void ece_partial(
    const float* __restrict__ conf,
    const int*   __restrict__ pred,
    const int*   __restrict__ targ,
    const int*   __restrict__ mask,
    unsigned long long* __restrict__ ws,
    int nvec)
{
    // Block-level merge buffers only -- NO LDS ops in the hot loop.
    __shared__ unsigned int hsum[16];          // wrapped-i32 per-bin block sums
    __shared__ unsigned long long stot;

    const int tid  = threadIdx.x;
    const int lane = tid & 63;

    if (tid < 16) hsum[tid] = 0u;
    if (tid == 0) stot = 0ULL;
    __syncthreads();

    const int gid    = blockIdx.x * blockDim.x + tid;
    const int stride = gridDim.x * blockDim.x;

    const f32x4* __restrict__ c4p = (const f32x4*)conf;
    const i32x4* __restrict__ p4p = (const i32x4*)pred;
    const i32x4* __restrict__ t4p = (const i32x4*)targ;
    const i32x4* __restrict__ m4p = (const i32x4*)mask;

    // 15 private accumulators, ALL indexing compile-time after unroll.
    int acc[NBINS];
#pragma unroll
    for (int b = 0; b < NBINS; ++b) acc[b] = 0;

    unsigned int tot = 0;

    int i = gid;
    for (; i + stride < nvec; i += 2 * stride) {
        const int j = i + stride;
        // Non-temporal: single-touch stream; R5 measured -31% vs cached loads.
        f32x4 c0 = __builtin_nontemporal_load(c4p + i);
        f32x4 c1 = __builtin_nontemporal_load(c4p + j);
        i32x4 p0 = __builtin_nontemporal_load(p4p + i);
        i32x4 p1 = __builtin_nontemporal_load(p4p + j);
        i32x4 t0 = __builtin_nontemporal_load(t4p + i);
        i32x4 t1 = __builtin_nontemporal_load(t4p + j);
        i32x4 m0 = __builtin_nontemporal_load(m4p + i);
        i32x4 m1 = __builtin_nontemporal_load(m4p + j);
        // Keep all 8 vector loads issued before consumption (MLP).
        asm volatile("" : "+v"(c0), "+v"(c1), "+v"(p0), "+v"(p1),
                          "+v"(t0), "+v"(t1), "+v"(m0), "+v"(m1));

#pragma unroll
        for (int k = 0; k < 4; ++k) {
            float c = c0[k];
            int   m = m0[k];
            tot += (unsigned int)m;
            bool valid = (m != 0) & (c > 0.0f) & (c <= 1.0f);
            int bin = (int)ceilf(c * 15.0f) - 1;
            bin = min(max(bin, 0), NBINS - 1);
            bin = valid ? bin : -1;                       // -1 matches no bin
            float corr = (p0[k] == t0[k]) ? 1.0f : 0.0f;
            int d = (int)rintf((c - corr) * 65536.0f);    // |d| <= 65536
#pragma unroll
            for (int b = 0; b < NBINS; ++b)
                acc[b] += (bin == b) ? d : 0;             // branchless select
        }
#pragma unroll
        for (int k = 0; k < 4; ++k) {
            float c = c1[k];
            int   m = m1[k];
            tot += (unsigned int)m;
            bool valid = (m != 0) & (c > 0.0f) & (c <= 1.0f);
            int bin = (int)ceilf(c * 15.0f) - 1;
            bin = min(max(bin, 0), NBINS - 1);
            bin = valid ? bin : -1;
            float corr = (p1[k] == t1[k]) ? 1.0f : 0.0f;
            int d = (int)rintf((c - corr) * 65536.0f);
#pragma unroll
            for (int b = 0; b < NBINS; ++b)
                acc[b] += (bin == b) ? d : 0;
        }
    }
    for (; i < nvec; i += stride) {
        f32x4 c0 = __builtin_nontemporal_load(c4p + i);
        i32x4 p0 = __builtin_nontemporal_load(p4p + i);
        i32x4 t0 = __builtin_nontemporal_load(t4p + i);
        i32x4 m0 = __builtin_nontemporal_load(m4p + i);
#pragma unroll
        for (int k = 0; k < 4; ++k) {
            float c = c0[k];
            int   m = m0[k];
            tot += (unsigned int)m;
            bool valid = (m != 0) & (c > 0.0f) & (c <= 1.0f);
            int bin = (int)ceilf(c * 15.0f) - 1;
            bin = min(max(bin, 0), NBINS - 1);
            bin = valid ? bin : -1;
            float corr = (p0[k] == t0[k]) ? 1.0f : 0.0f;
            int d = (int)rintf((c - corr) * 65536.0f);
#pragma unroll
            for (int b = 0; b < NBINS; ++b)
                acc[b] += (bin == b) ? d : 0;
        }
    }

    // Once-per-block merge. Wave shuffle-reduce each accumulator, then the
    // wave leader does 15 LDS atomics (4 waves x 15 RMWs -- negligible).
#pragma unroll
    for (int b = 0; b < NBINS; ++b) {
        int v = acc[b];
#pragma unroll
        for (int off = 32; off; off >>= 1) v += __shfl_down(v, off, 64);
        acc[b] = v;
    }
    unsigned int v = tot;
#pragma unroll
    for (int off = 32; off; off >>= 1) v += __shfl_down(v, off, 64);

    if (lane == 0) {
#pragma unroll
        for (int b = 0; b < NBINS; ++b)
            if (acc[b] != 0) atomicAdd(&hsum[b], (unsigned int)acc[b]);
        atomicAdd(&stot, (unsigned long long)v);
    }
    __syncthreads();

    if (tid < NBINS) {
        int s = (int)hsum[tid];   // block |sum| <= 2^30, fits i32
        if (s != 0)
            atomicAdd(&ws[tid], (unsigned long long)(long long)s);
    }
    if (tid == 0) {
        unsigned long long s = stot;
        if (s) atomicAdd(&ws[NBINS], s);
    }
}

__global__ void ece_scalar_tail(const float* __restrict__ conf,
                                const int*   __restrict__ pred,
                                const int*   __restrict__ targ,
                                const int*   __restrict__ mask,
                                unsigned long long* __restrict__ ws,
                                long long start, long long n)
{
    long long i = start + threadIdx.x;
    if (i < n) {
        float c = conf[i];
        int   m = mask[i];
        if (m) atomicAdd(&ws[NBINS], 1ULL);
        if ((m != 0) & (c > 0.0f) & (c <= 1.0f)) {
            int bin = (int)ceilf(c * 15.0f) - 1;
            bin = min(max(bin, 0), NBINS - 1);
            float corr = (pred[i] == targ[i]) ? 1.0f : 0.0f;
            int d = (int)rintf((c - corr) * 65536.0f);
            atomicAdd(&ws[bin], (unsigned long long)(long long)d);
        }
    }
}

__global__ void ece_final(const unsigned long long* __restrict__ ws,
                          float* __restrict__ out)
{
    int tid = threadIdx.x; // 64 threads
    double v = 0.0;
    if (tid < NBINS) {
        long long s = (long long)ws[tid];
        v = fabs((double)s);
    }
#pragma unroll
    for (int off = 32; off; off >>= 1) v += __shfl_down(v, off, 64);
    if (tid == 0) {
        double total = (double)ws[NBINS];
        if (total < 1.0) total = 1.0;
        out[0] = (float)(v * (1.0 / 65536.0) / total);
    }
}

extern "C" void kernel_launch(void* const* d_in, const int* in_sizes, int n_in,
                              void* d_out, int out_size, void* d_ws, size_t ws_size,
                              hipStream_t stream)
{
    const float* conf = (const float*)d_in[0];
    const int*   pred = (const int*)d_in[1];
    const int*   targ = (const int*)d_in[2];
    const int*   mask = (const int*)d_in[3];
    long long n    = in_sizes[0];
    int       nvec = (int)(n / 4);

    unsigned long long* ws = (unsigned long long*)d_ws;

    // Zero the 16 u64 accumulators every call (deterministic; capture-safe).
    hipMemsetAsync(d_ws, 0, (NBINS + 1) * sizeof(unsigned long long), stream);

    // 2048 blocks x 256 threads = 8 blocks/CU = 32 waves/CU (full occupancy);
    // 64 elements/thread = exactly 8 two-chunk iterations.
    ece_partial<<<2048, 256, 0, stream>>>(conf, pred, targ, mask, ws, nvec);
    if (n % 4 != 0) {
        ece_scalar_tail<<<1, 64, 0, stream>>>(conf, pred, targ, mask, ws,
                                              (long long)nvec * 4, n);
    }
    ece_final<<<1, 64, 0, stream>>>(ws, (float*)d_out);
}

// Round 7
// 117.791 us; speedup vs baseline: 1.1613x; 1.1613x over previous
//
#include <hip/hip_runtime.h>

#define NBINS 15

typedef float f32x4 __attribute__((ext_vector_type(4)));
typedef int   i32x4 __attribute__((ext_vector_type(4)));

// Workspace layout (u64 each): [0..14] per-bin signed sum of wv*(c-corr) in
// 2^-16 fixed point (two's-complement wrapped), [15] total mask sum.
// ECE = sum_b |S_b| / 2^16 / total.  (counts/safe are provably redundant:
// empty bins contribute 0 in both formulations.)

__global__ __launch_bounds__(256, 7) void ece_partial(
    const float* __restrict__ conf,
    const int*   __restrict__ pred,
    const int*   __restrict__ targ,
    const int*   __restrict__ mask,
    unsigned long long* __restrict__ ws,
    int nvec)
{
    // Block-level merge buffers only -- NO LDS ops in the hot loop.
    __shared__ unsigned int hsum[16];          // wrapped-i32 per-bin block sums
    __shared__ unsigned long long stot;

    const int tid  = threadIdx.x;
    const int lane = tid & 63;

    if (tid < 16) hsum[tid] = 0u;
    if (tid == 0) stot = 0ULL;
    __syncthreads();

    const int gid    = blockIdx.x * blockDim.x + tid;
    const int stride = gridDim.x * blockDim.x;

    const f32x4* __restrict__ c4p = (const f32x4*)conf;
    const i32x4* __restrict__ p4p = (const i32x4*)pred;
    const i32x4* __restrict__ t4p = (const i32x4*)targ;
    const i32x4* __restrict__ m4p = (const i32x4*)mask;

    // 15 private accumulators, ALL indexing compile-time after unroll.
    int acc[NBINS];
#pragma unroll
    for (int b = 0; b < NBINS; ++b) acc[b] = 0;

    unsigned int tot = 0;

    int i = gid;
    for (; i + stride < nvec; i += 2 * stride) {
        const int j = i + stride;
        // Non-temporal: single-touch stream; R5 measured -31% vs cached loads.
        f32x4 c0 = __builtin_nontemporal_load(c4p + i);
        f32x4 c1 = __builtin_nontemporal_load(c4p + j);
        i32x4 p0 = __builtin_nontemporal_load(p4p + i);
        i32x4 p1 = __builtin_nontemporal_load(p4p + j);
        i32x4 t0 = __builtin_nontemporal_load(t4p + i);
        i32x4 t1 = __builtin_nontemporal_load(t4p + j);
        i32x4 m0 = __builtin_nontemporal_load(m4p + i);
        i32x4 m1 = __builtin_nontemporal_load(m4p + j);
        // Keep all 8 vector loads issued before consumption (MLP).
        asm volatile("" : "+v"(c0), "+v"(c1), "+v"(p0), "+v"(p1),
                          "+v"(t0), "+v"(t1), "+v"(m0), "+v"(m1));

#pragma unroll
        for (int k = 0; k < 4; ++k) {
            float c = c0[k];
            int   m = m0[k];
            tot += (unsigned int)m;
            bool valid = (m != 0) & (c > 0.0f) & (c <= 1.0f);
            int bin = (int)ceilf(c * 15.0f) - 1;
            bin = min(max(bin, 0), NBINS - 1);
            bin = valid ? bin : -1;                       // -1 matches no bin
            float corr = (p0[k] == t0[k]) ? 1.0f : 0.0f;
            int d = (int)rintf((c - corr) * 65536.0f);    // |d| <= 65536
#pragma unroll
            for (int b = 0; b < NBINS; ++b)
                acc[b] += (bin == b) ? d : 0;             // branchless select
        }
#pragma unroll
        for (int k = 0; k < 4; ++k) {
            float c = c1[k];
            int   m = m1[k];
            tot += (unsigned int)m;
            bool valid = (m != 0) & (c > 0.0f) & (c <= 1.0f);
            int bin = (int)ceilf(c * 15.0f) - 1;
            bin = min(max(bin, 0), NBINS - 1);
            bin = valid ? bin : -1;
            float corr = (p1[k] == t1[k]) ? 1.0f : 0.0f;
            int d = (int)rintf((c - corr) * 65536.0f);
#pragma unroll
            for (int b = 0; b < NBINS; ++b)
                acc[b] += (bin == b) ? d : 0;
        }
    }
    for (; i < nvec; i += stride) {
        f32x4 c0 = __builtin_nontemporal_load(c4p + i);
        i32x4 p0 = __builtin_nontemporal_load(p4p + i);
        i32x4 t0 = __builtin_nontemporal_load(t4p + i);
        i32x4 m0 = __builtin_nontemporal_load(m4p + i);
#pragma unroll
        for (int k = 0; k < 4; ++k) {
            float c = c0[k];
            int   m = m0[k];
            tot += (unsigned int)m;
            bool valid = (m != 0) & (c > 0.0f) & (c <= 1.0f);
            int bin = (int)ceilf(c * 15.0f) - 1;
            bin = min(max(bin, 0), NBINS - 1);
            bin = valid ? bin : -1;
            float corr = (p0[k] == t0[k]) ? 1.0f : 0.0f;
            int d = (int)rintf((c - corr) * 65536.0f);
#pragma unroll
            for (int b = 0; b < NBINS; ++b)
                acc[b] += (bin == b) ? d : 0;
        }
    }

    // Once-per-block merge. Wave shuffle-reduce each accumulator, then the
    // wave leader does 15 LDS atomics (4 waves x 15 RMWs -- negligible).
#pragma unroll
    for (int b = 0; b < NBINS; ++b) {
        int v = acc[b];
#pragma unroll
        for (int off = 32; off; off >>= 1) v += __shfl_down(v, off, 64);
        acc[b] = v;
    }
    unsigned int v = tot;
#pragma unroll
    for (int off = 32; off; off >>= 1) v += __shfl_down(v, off, 64);

    if (lane == 0) {
#pragma unroll
        for (int b = 0; b < NBINS; ++b)
            if (acc[b] != 0) atomicAdd(&hsum[b], (unsigned int)acc[b]);
        atomicAdd(&stot, (unsigned long long)v);
    }
    __syncthreads();

    if (tid < NBINS) {
        int s = (int)hsum[tid];   // block |sum| <= 2^30, fits i32
        if (s != 0)
            atomicAdd(&ws[tid], (unsigned long long)(long long)s);
    }
    if (tid == 0) {
        unsigned long long s = stot;
        if (s) atomicAdd(&ws[NBINS], s);
    }
}

__global__ void ece_scalar_tail(const float* __restrict__ conf,
                                const int*   __restrict__ pred,
                                const int*   __restrict__ targ,
                                const int*   __restrict__ mask,
                                unsigned long long* __restrict__ ws,
                                long long start, long long n)
{
    long long i = start + threadIdx.x;
    if (i < n) {
        float c = conf[i];
        int   m = mask[i];
        if (m) atomicAdd(&ws[NBINS], 1ULL);
        if ((m != 0) & (c > 0.0f) & (c <= 1.0f)) {
            int bin = (int)ceilf(c * 15.0f) - 1;
            bin = min(max(bin, 0), NBINS - 1);
            float corr = (pred[i] == targ[i]) ? 1.0f : 0.0f;
            int d = (int)rintf((c - corr) * 65536.0f);
            atomicAdd(&ws[bin], (unsigned long long)(long long)d);
        }
    }
}

__global__ void ece_final(const unsigned long long* __restrict__ ws,
                          float* __restrict__ out)
{
    int tid = threadIdx.x; // 64 threads
    double v = 0.0;
    if (tid < NBINS) {
        long long s = (long long)ws[tid];
        v = fabs((double)s);
    }
#pragma unroll
    for (int off = 32; off; off >>= 1) v += __shfl_down(v, off, 64);
    if (tid == 0) {
        double total = (double)ws[NBINS];
        if (total < 1.0) total = 1.0;
        out[0] = (float)(v * (1.0 / 65536.0) / total);
    }
}

extern "C" void kernel_launch(void* const* d_in, const int* in_sizes, int n_in,
                              void* d_out, int out_size, void* d_ws, size_t ws_size,
                              hipStream_t stream)
{
    const float* conf = (const float*)d_in[0];
    const int*   pred = (const int*)d_in[1];
    const int*   targ = (const int*)d_in[2];
    const int*   mask = (const int*)d_in[3];
    long long n    = in_sizes[0];
    int       nvec = (int)(n / 4);

    unsigned long long* ws = (unsigned long long*)d_ws;

    // Zero the 16 u64 accumulators every call (deterministic; capture-safe).
    hipMemsetAsync(d_ws, 0, (NBINS + 1) * sizeof(unsigned long long), stream);

    // 1792 blocks x 256 threads = 7 blocks/CU = 28 waves/CU.
    // launch_bounds(256,7) caps VGPR at 73 -- above the ~60 live values, so
    // no spill (R6's (256,8) cap of 64 spilled: WRITE_SIZE 240B -> 26.5MB).
    ece_partial<<<1792, 256, 0, stream>>>(conf, pred, targ, mask, ws, nvec);
    if (n % 4 != 0) {
        ece_scalar_tail<<<1, 64, 0, stream>>>(conf, pred, targ, mask, ws,
                                              (long long)nvec * 4, n);
    }
    ece_final<<<1, 64, 0, stream>>>(ws, (float*)d_out);
}

// Round 8
// 113.014 us; speedup vs baseline: 1.2103x; 1.0423x over previous
//
#include <hip/hip_runtime.h>

#define NBINS 15

typedef float f32x4 __attribute__((ext_vector_type(4)));
typedef int   i32x4 __attribute__((ext_vector_type(4)));

// Workspace layout (u64 each): [0..14] per-bin signed sum of wv*(c-corr) in
// 2^-16 fixed point (two's-complement wrapped), [15] total mask sum.
// ECE = sum_b |S_b| / 2^16 / total.

// Process one float4/int4 chunk into acc[]/tot (branchless 15-way select).
#define PROC(cv, pv, tv, mv)                                              \
    {                                                                     \
        _Pragma("unroll")                                                 \
        for (int k = 0; k < 4; ++k) {                                     \
            float c = (cv)[k];                                            \
            int   m = (mv)[k];                                            \
            tot += (unsigned int)m;                                       \
            bool valid = (m != 0) & (c > 0.0f) & (c <= 1.0f);             \
            int bin = (int)ceilf(c * 15.0f) - 1;                          \
            bin = min(max(bin, 0), NBINS - 1);                            \
            bin = valid ? bin : -1;                                       \
            float corr = ((pv)[k] == (tv)[k]) ? 1.0f : 0.0f;              \
            int d = (int)rintf((c - corr) * 65536.0f);                    \
            _Pragma("unroll")                                             \
            for (int b = 0; b < NBINS; ++b)                               \
                acc[b] += (bin == b) ? d : 0;                             \
        }                                                                 \
    }

__global__ __launch_bounds__(256, 6) void ece_partial(
    const float* __restrict__ conf,
    const int*   __restrict__ pred,
    const int*   __restrict__ targ,
    const int*   __restrict__ mask,
    unsigned long long* __restrict__ ws,
    int nvec)
{
    __shared__ unsigned int hsum[16];
    __shared__ unsigned long long stot;

    const int tid  = threadIdx.x;
    const int lane = tid & 63;

    if (tid < 16) hsum[tid] = 0u;
    if (tid == 0) stot = 0ULL;
    __syncthreads();

    const int gid    = blockIdx.x * blockDim.x + tid;
    const int stride = gridDim.x * blockDim.x;

    const f32x4* __restrict__ c4p = (const f32x4*)conf;
    const i32x4* __restrict__ p4p = (const i32x4*)pred;
    const i32x4* __restrict__ t4p = (const i32x4*)targ;
    const i32x4* __restrict__ m4p = (const i32x4*)mask;

    int acc[NBINS];
#pragma unroll
    for (int b = 0; b < NBINS; ++b) acc[b] = 0;

    unsigned int tot = 0;

    // Two-stage software pipeline: while computing stage X, the other
    // stage's 4 nt loads are in flight. No asm pin -> the compiler can
    // wait with graded vmcnt(4) per stage instead of a vmcnt(0) drain
    // (R5's pin forced a full drain before each compute burst).
    int k = gid;
    if (k + stride < nvec) {
        f32x4 c0 = __builtin_nontemporal_load(c4p + k);
        i32x4 p0 = __builtin_nontemporal_load(p4p + k);
        i32x4 t0 = __builtin_nontemporal_load(t4p + k);
        i32x4 m0 = __builtin_nontemporal_load(m4p + k);
        f32x4 c1 = __builtin_nontemporal_load(c4p + (k + stride));
        i32x4 p1 = __builtin_nontemporal_load(p4p + (k + stride));
        i32x4 t1 = __builtin_nontemporal_load(t4p + (k + stride));
        i32x4 m1 = __builtin_nontemporal_load(m4p + (k + stride));

        for (; k + 3 * stride < nvec; k += 2 * stride) {
            PROC(c0, p0, t0, m0);
            {
                const int n0 = k + 2 * stride;
                c0 = __builtin_nontemporal_load(c4p + n0);
                p0 = __builtin_nontemporal_load(p4p + n0);
                t0 = __builtin_nontemporal_load(t4p + n0);
                m0 = __builtin_nontemporal_load(m4p + n0);
            }
            PROC(c1, p1, t1, m1);
            {
                const int n1 = k + 3 * stride;
                c1 = __builtin_nontemporal_load(c4p + n1);
                p1 = __builtin_nontemporal_load(p4p + n1);
                t1 = __builtin_nontemporal_load(t4p + n1);
                m1 = __builtin_nontemporal_load(m4p + n1);
            }
        }
        // Drain the two live stages (indices k, k+stride).
        PROC(c0, p0, t0, m0);
        PROC(c1, p1, t1, m1);
        k += 2 * stride;
    }
    // Tail: at most one leftover chunk per thread (plus the no-pipeline case).
    for (; k < nvec; k += stride) {
        f32x4 cz = __builtin_nontemporal_load(c4p + k);
        i32x4 pz = __builtin_nontemporal_load(p4p + k);
        i32x4 tz = __builtin_nontemporal_load(t4p + k);
        i32x4 mz = __builtin_nontemporal_load(m4p + k);
        PROC(cz, pz, tz, mz);
    }

    // Once-per-block merge.
#pragma unroll
    for (int b = 0; b < NBINS; ++b) {
        int v = acc[b];
#pragma unroll
        for (int off = 32; off; off >>= 1) v += __shfl_down(v, off, 64);
        acc[b] = v;
    }
    unsigned int v = tot;
#pragma unroll
    for (int off = 32; off; off >>= 1) v += __shfl_down(v, off, 64);

    if (lane == 0) {
#pragma unroll
        for (int b = 0; b < NBINS; ++b)
            if (acc[b] != 0) atomicAdd(&hsum[b], (unsigned int)acc[b]);
        atomicAdd(&stot, (unsigned long long)v);
    }
    __syncthreads();

    if (tid < NBINS) {
        int s = (int)hsum[tid];
        if (s != 0)
            atomicAdd(&ws[tid], (unsigned long long)(long long)s);
    }
    if (tid == 0) {
        unsigned long long s = stot;
        if (s) atomicAdd(&ws[NBINS], s);
    }
}

__global__ void ece_scalar_tail(const float* __restrict__ conf,
                                const int*   __restrict__ pred,
                                const int*   __restrict__ targ,
                                const int*   __restrict__ mask,
                                unsigned long long* __restrict__ ws,
                                long long start, long long n)
{
    long long i = start + threadIdx.x;
    if (i < n) {
        float c = conf[i];
        int   m = mask[i];
        if (m) atomicAdd(&ws[NBINS], 1ULL);
        if ((m != 0) & (c > 0.0f) & (c <= 1.0f)) {
            int bin = (int)ceilf(c * 15.0f) - 1;
            bin = min(max(bin, 0), NBINS - 1);
            float corr = (pred[i] == targ[i]) ? 1.0f : 0.0f;
            int d = (int)rintf((c - corr) * 65536.0f);
            atomicAdd(&ws[bin], (unsigned long long)(long long)d);
        }
    }
}

__global__ void ece_final(const unsigned long long* __restrict__ ws,
                          float* __restrict__ out)
{
    int tid = threadIdx.x; // 64 threads
    double v = 0.0;
    if (tid < NBINS) {
        long long s = (long long)ws[tid];
        v = fabs((double)s);
    }
#pragma unroll
    for (int off = 32; off; off >>= 1) v += __shfl_down(v, off, 64);
    if (tid == 0) {
        double total = (double)ws[NBINS];
        if (total < 1.0) total = 1.0;
        out[0] = (float)(v * (1.0 / 65536.0) / total);
    }
}

extern "C" void kernel_launch(void* const* d_in, const int* in_sizes, int n_in,
                              void* d_out, int out_size, void* d_ws, size_t ws_size,
                              hipStream_t stream)
{
    const float* conf = (const float*)d_in[0];
    const int*   pred = (const int*)d_in[1];
    const int*   targ = (const int*)d_in[2];
    const int*   mask = (const int*)d_in[3];
    long long n    = in_sizes[0];
    int       nvec = (int)(n / 4);

    unsigned long long* ws = (unsigned long long*)d_ws;

    // Zero the 16 u64 accumulators every call (deterministic; capture-safe).
    hipMemsetAsync(d_ws, 0, (NBINS + 1) * sizeof(unsigned long long), stream);

    // 1536 blocks x 256 threads = 6 blocks/CU (R5's best point; 7 and 8
    // blocks/CU measured worse). (256,6) caps VGPR at 85; pipeline needs
    // ~60 -> no spill (guard: WRITE_SIZE stays ~bytes-of-result).
    ece_partial<<<1536, 256, 0, stream>>>(conf, pred, targ, mask, ws, nvec);
    if (n % 4 != 0) {
        ece_scalar_tail<<<1, 64, 0, stream>>>(conf, pred, targ, mask, ws,
                                              (long long)nvec * 4, n);
    }
    ece_final<<<1, 64, 0, stream>>>(ws, (float*)d_out);
}